// Round 8
// baseline (44.178 us; speedup 1.0000x reference)
//
#include <hip/hip_runtime.h>

#define N   1024
#define HD  64
#define MD  32
#define BLK 256
#define WROW (2 * HD + 1)   // 129, w_msg row stride

// ---------------------------------------------------------------------------
// P0: h0 = feat + posenc; A1/B1 projections. One block per 4 rows.
// ---------------------------------------------------------------------------
__global__ __launch_bounds__(BLK) void k_p0(const float* __restrict__ feat,
                                            const float* __restrict__ wmsg,
                                            const float* __restrict__ bmsg,
                                            float* __restrict__ h0,
                                            float* __restrict__ A,
                                            float* __restrict__ Bb)
{
    __shared__ float scr[4160 + 4 * HD];
    const int tid = threadIdx.x;
    const int n0  = blockIdx.x * 4;

    for (int u = tid; u < MD * WROW; u += BLK) scr[u] = wmsg[u];   // 4128 floats
    float* hrow = scr + 4160;
    {
        const int n = n0 + (tid >> 6), d = tid & 63;
        const float div = expf((float)(d & ~1) * (-9.210340371976184f / 64.0f));
        const float ang = (float)n * div;
        const float pe  = (d & 1) ? cosf(ang) : sinf(ang);
        const float hv  = feat[n * HD + d] + pe;
        h0[n * HD + d] = hv;
        hrow[tid] = hv;
    }
    __syncthreads();
    if (tid < 4 * MD) {
        const int nl = tid >> 5, m = tid & 31;
        const float* wa = scr + m * WROW;          // stride 129: conflict-free
        const float* hr = hrow + nl * HD;
        float sa = 0.f, sb = bmsg[m];
#pragma unroll
        for (int c = 0; c < HD; c++) {
            const float hv = hr[c];
            sa = fmaf(hv, wa[c], sa);
            sb = fmaf(hv, wa[HD + c], sb);
        }
        const int n = n0 + nl;
        A[n * MD + m]  = sa;
        Bb[n * MD + m] = sb;
    }
}

// ---------------------------------------------------------------------------
// Pair kernel: one block (256 thr) per row-pair (iA, iB = iA + N/2).
// Lane map: kq = lane>>3 (4 k's each, float4), jslot = lane&7 (8 j/iter/wave).
// Wave w owns j in [w*256, w*256+256).  Per iter: ONE coalesced float4 A-load
// per lane (wave covers A[8j][32k] = 1KB exactly) + 2 broadcast ds_read_b128.
// m = relu(A[j][k] + Bi[k] + d2*wd[k]);  P[k][c] += m * r_c ; wp folded after.
// x_out[i] = x[i] + (S_k wp_ck P_kc + bp_c (Sx_c - N x_ic)) / (N-1)
// LAYER1 additionally computes msum rows (diag-corrected), then h1 = relu(
// [h0,msum]@wf.T+bf) and the layer-2 A2/B2 rows for iA,iB — fusing old k_p2.
// ---------------------------------------------------------------------------
template<int LAYER1>
__global__ __launch_bounds__(BLK) void k_pair(
    const float* __restrict__ xsrc, const float* __restrict__ Aap,
    const float* __restrict__ Bbp, const float* __restrict__ wmsg,
    const float* __restrict__ wpos, const float* __restrict__ bpos,
    float* __restrict__ xout,
    const float* __restrict__ h0, const float* __restrict__ wf,
    const float* __restrict__ bf, const float* __restrict__ wmsg2,
    const float* __restrict__ bmsg2, float* __restrict__ A2,
    float* __restrict__ B2)
{
    const int tid   = threadIdx.x;
    const int wid   = tid >> 6;
    const int lane  = tid & 63;
    const int jslot = lane & 7;
    const int kq    = lane >> 3;        // k = kq*4 .. kq*4+3

    __shared__ float4 rdA[N];           // 16 KB (reused as scr in LAYER1 tail)
    __shared__ float4 rdB[N];           // 16 KB
    __shared__ float  wacc[4][8];
    __shared__ float  msAl[4][MD];
    __shared__ float  msBl[4][MD];
    __shared__ float  SxL[3];
    __shared__ float  msF[2][MD];
    __shared__ float  h0r[2][HD];
    __shared__ float  h1r[2][HD];

    const int iA = blockIdx.x, iB = blockIdx.x + N / 2;
    const float xiA0 = xsrc[iA * 3 + 0], xiA1 = xsrc[iA * 3 + 1], xiA2 = xsrc[iA * 3 + 2];
    const float xiB0 = xsrc[iB * 3 + 0], xiB1 = xsrc[iB * 3 + 1], xiB2 = xsrc[iB * 3 + 2];

    // ---- stage r/d2 tables for both rows; accumulate column-sum of x ----
    float sx0 = 0.f, sx1 = 0.f, sx2 = 0.f;
#pragma unroll
    for (int q = 0; q < N / BLK; q++) {
        const int j = q * BLK + tid;
        const float xj0 = xsrc[j * 3 + 0];
        const float xj1 = xsrc[j * 3 + 1];
        const float xj2 = xsrc[j * 3 + 2];
        sx0 += xj0; sx1 += xj1; sx2 += xj2;
        float r0 = xj0 - xiA0, r1 = xj1 - xiA1, r2 = xj2 - xiA2;
        rdA[j] = make_float4(r0, r1, r2, fmaf(r0, r0, fmaf(r1, r1, r2 * r2)));
        r0 = xj0 - xiB0; r1 = xj1 - xiB1; r2 = xj2 - xiB2;
        rdB[j] = make_float4(r0, r1, r2, fmaf(r0, r0, fmaf(r1, r1, r2 * r2)));
    }
#pragma unroll
    for (int off = 32; off > 0; off >>= 1) {
        sx0 += __shfl_xor(sx0, off);
        sx1 += __shfl_xor(sx1, off);
        sx2 += __shfl_xor(sx2, off);
    }
    if (lane == 0) { wacc[wid][0] = sx0; wacc[wid][1] = sx1; wacc[wid][2] = sx2; }
    __syncthreads();                       // rd tables + sx partials ready
    if (tid == 0) {
        SxL[0] = wacc[0][0] + wacc[1][0] + wacc[2][0] + wacc[3][0];
        SxL[1] = wacc[0][1] + wacc[1][1] + wacc[2][1] + wacc[3][1];
        SxL[2] = wacc[0][2] + wacc[1][2] + wacc[2][2] + wacc[3][2];
    }

    // ---- per-lane weights for the 4 owned k's (float4 where contiguous) ----
    const float4 biA4 = *(const float4*)(Bbp + iA * MD + kq * 4);
    const float4 biB4 = *(const float4*)(Bbp + iB * MD + kq * 4);
    const float4 wpx4 = *(const float4*)(wpos + kq * 4);
    const float4 wpy4 = *(const float4*)(wpos + MD + kq * 4);
    const float4 wpz4 = *(const float4*)(wpos + 2 * MD + kq * 4);
    float wd4[4];
#pragma unroll
    for (int kk = 0; kk < 4; kk++) wd4[kk] = wmsg[(kq * 4 + kk) * WROW + 2 * HD];
    const float biA[4] = {biA4.x, biA4.y, biA4.z, biA4.w};
    const float biB[4] = {biB4.x, biB4.y, biB4.z, biB4.w};
    const float wpx[4] = {wpx4.x, wpx4.y, wpx4.z, wpx4.w};
    const float wpy[4] = {wpy4.x, wpy4.y, wpy4.z, wpy4.w};
    const float wpz[4] = {wpz4.x, wpz4.y, wpz4.z, wpz4.w};

    float PAx[4] = {0,0,0,0}, PAy[4] = {0,0,0,0}, PAz[4] = {0,0,0,0};
    float PBx[4] = {0,0,0,0}, PBy[4] = {0,0,0,0}, PBz[4] = {0,0,0,0};
    float msA[4] = {0,0,0,0}, msB[4] = {0,0,0,0};

    const int jb = wid * (N / 4);          // 256 j per wave
#pragma unroll 4
    for (int it = 0; it < N / 4 / 8; it++) {
        const int j = jb + it * 8 + jslot;
        const float4 a4 = *(const float4*)(Aap + j * MD + kq * 4);
        const float4 fA = rdA[j];          // 8-way broadcast per address
        const float4 fB = rdB[j];
        const float av[4] = {a4.x, a4.y, a4.z, a4.w};
#pragma unroll
        for (int kk = 0; kk < 4; kk++) {
            const float mA = fmaxf(fmaf(fA.w, wd4[kk], av[kk] + biA[kk]), 0.f);
            const float mB = fmaxf(fmaf(fB.w, wd4[kk], av[kk] + biB[kk]), 0.f);
            if (LAYER1) { msA[kk] += mA; msB[kk] += mB; }
            PAx[kk] = fmaf(mA, fA.x, PAx[kk]);
            PAy[kk] = fmaf(mA, fA.y, PAy[kk]);
            PAz[kk] = fmaf(mA, fA.z, PAz[kk]);
            PBx[kk] = fmaf(mB, fB.x, PBx[kk]);
            PBy[kk] = fmaf(mB, fB.y, PBy[kk]);
            PBz[kk] = fmaf(mB, fB.z, PBz[kk]);
        }
    }

    // ---- fold wp per lane, then reduce across 64 lanes ----
    float vA0 = 0.f, vA1 = 0.f, vA2 = 0.f, vB0 = 0.f, vB1 = 0.f, vB2 = 0.f;
#pragma unroll
    for (int kk = 0; kk < 4; kk++) {
        vA0 = fmaf(PAx[kk], wpx[kk], vA0);
        vA1 = fmaf(PAy[kk], wpy[kk], vA1);
        vA2 = fmaf(PAz[kk], wpz[kk], vA2);
        vB0 = fmaf(PBx[kk], wpx[kk], vB0);
        vB1 = fmaf(PBy[kk], wpy[kk], vB1);
        vB2 = fmaf(PBz[kk], wpz[kk], vB2);
    }
#pragma unroll
    for (int off = 32; off > 0; off >>= 1) {
        vA0 += __shfl_xor(vA0, off); vA1 += __shfl_xor(vA1, off); vA2 += __shfl_xor(vA2, off);
        vB0 += __shfl_xor(vB0, off); vB1 += __shfl_xor(vB1, off); vB2 += __shfl_xor(vB2, off);
    }
    if (LAYER1) {
        // reduce msum over the 8 jslots (lane bits 0..2)
#pragma unroll
        for (int off = 1; off <= 4; off <<= 1) {
#pragma unroll
            for (int kk = 0; kk < 4; kk++) {
                msA[kk] += __shfl_xor(msA[kk], off);
                msB[kk] += __shfl_xor(msB[kk], off);
            }
        }
    }
    __syncthreads();                       // SxL consumed; wacc reusable
    if (lane == 0) {
        wacc[wid][0] = vA0; wacc[wid][1] = vA1; wacc[wid][2] = vA2;
        wacc[wid][3] = vB0; wacc[wid][4] = vB1; wacc[wid][5] = vB2;
    }
    if (LAYER1 && jslot == 0) {
#pragma unroll
        for (int kk = 0; kk < 4; kk++) {
            msAl[wid][kq * 4 + kk] = msA[kk];
            msBl[wid][kq * 4 + kk] = msB[kk];
        }
    }
    __syncthreads();                       // epilogue data ready

    if (tid == 0) {
        const float bp0 = bpos[0], bp1 = bpos[1], bp2 = bpos[2];
        float aA0 = wacc[0][0] + wacc[1][0] + wacc[2][0] + wacc[3][0];
        float aA1 = wacc[0][1] + wacc[1][1] + wacc[2][1] + wacc[3][1];
        float aA2 = wacc[0][2] + wacc[1][2] + wacc[2][2] + wacc[3][2];
        float aB0 = wacc[0][3] + wacc[1][3] + wacc[2][3] + wacc[3][3];
        float aB1 = wacc[0][4] + wacc[1][4] + wacc[2][4] + wacc[3][4];
        float aB2 = wacc[0][5] + wacc[1][5] + wacc[2][5] + wacc[3][5];
        const float inv = 1.0f / 1023.0f;
        xout[iA * 3 + 0] = xiA0 + (aA0 + bp0 * (SxL[0] - (float)N * xiA0)) * inv;
        xout[iA * 3 + 1] = xiA1 + (aA1 + bp1 * (SxL[1] - (float)N * xiA1)) * inv;
        xout[iA * 3 + 2] = xiA2 + (aA2 + bp2 * (SxL[2] - (float)N * xiA2)) * inv;
        xout[iB * 3 + 0] = xiB0 + (aB0 + bp0 * (SxL[0] - (float)N * xiB0)) * inv;
        xout[iB * 3 + 1] = xiB1 + (aB1 + bp1 * (SxL[1] - (float)N * xiB1)) * inv;
        xout[iB * 3 + 2] = xiB2 + (aB2 + bp2 * (SxL[2] - (float)N * xiB2)) * inv;
    }

    if (LAYER1) {
        // ---- fused h-update + layer-2 A/B projections for rows iA, iB ----
        float* scr = (float*)rdA;          // 8192 floats free after main loop
        if (tid < 2 * MD) {                // msum rows with diagonal correction
            const int row = tid >> 5, k = tid & 31;
            const int i = row ? iB : iA;
            const float (*ml)[MD] = row ? msBl : msAl;
            float s = ml[0][k] + ml[1][k] + ml[2][k] + ml[3][k];
            s -= fmaxf(Aap[i * MD + k] + Bbp[i * MD + k], 0.f);   // d2=0 at j==i
            msF[row][k] = s;
        }
        for (int u = tid; u < HD * (HD + MD); u += BLK) {          // stage wf
            const int o = u / (HD + MD), c = u - o * (HD + MD);
            scr[o * 97 + c] = wf[u];
        }
        if (tid < 2 * HD) {
            const int row = tid >> 6, d = tid & 63;
            h0r[row][d] = h0[(row ? iB : iA) * HD + d];
        }
        __syncthreads();
        if (tid < 2 * HD) {                // h1 rows
            const int row = tid >> 6, o = tid & 63;
            const float* w = scr + o * 97;
            float s = bf[o];
#pragma unroll
            for (int c = 0; c < HD; c++) s = fmaf(h0r[row][c], w[c], s);
#pragma unroll
            for (int k = 0; k < MD; k++) s = fmaf(msF[row][k], w[HD + k], s);
            h1r[row][o] = fmaxf(s, 0.f);
        }
        __syncthreads();
        for (int u = tid; u < MD * WROW; u += BLK) scr[u] = wmsg2[u];
        __syncthreads();
        if (tid < 2 * MD) {                // A2/B2 rows
            const int row = tid >> 5, m = tid & 31;
            const float* wa = scr + m * WROW;
            const float* hr = h1r[row];
            float sa = 0.f, sb = bmsg2[m];
#pragma unroll
            for (int c = 0; c < HD; c++) {
                const float hv = hr[c];
                sa = fmaf(hv, wa[c], sa);
                sb = fmaf(hv, wa[HD + c], sb);
            }
            const int i = row ? iB : iA;
            A2[i * MD + m] = sa;
            B2[i * MD + m] = sb;
        }
    }
}

// ---------------------------------------------------------------------------
extern "C" void kernel_launch(void* const* d_in, const int* in_sizes, int n_in,
                              void* d_out, int out_size, void* d_ws, size_t ws_size,
                              hipStream_t stream)
{
    const float* pos     = (const float*)d_in[0];
    const float* feat    = (const float*)d_in[1];
    const float* w_msg1  = (const float*)d_in[3];
    const float* b_msg1  = (const float*)d_in[4];
    const float* w_pos1  = (const float*)d_in[5];
    const float* b_pos1  = (const float*)d_in[6];
    const float* w_feat1 = (const float*)d_in[7];
    const float* b_feat1 = (const float*)d_in[8];
    const float* w_msg2  = (const float*)d_in[9];
    const float* b_msg2  = (const float*)d_in[10];
    const float* w_pos2  = (const float*)d_in[11];
    const float* b_pos2  = (const float*)d_in[12];

    float* ws  = (float*)d_ws;
    float* h0  = ws;                 // N*HD
    float* A1  = h0  + N * HD;       // N*MD
    float* B1  = A1  + N * MD;
    float* x1  = B1  + N * MD;       // N*4 (padded)
    float* A2  = x1  + N * 4;
    float* B2  = A2  + N * MD;

    k_p0<<<N / 4, BLK, 0, stream>>>(feat, w_msg1, b_msg1, h0, A1, B1);
    k_pair<1><<<N / 2, BLK, 0, stream>>>(pos, A1, B1, w_msg1, w_pos1, b_pos1, x1,
                                         h0, w_feat1, b_feat1, w_msg2, b_msg2, A2, B2);
    k_pair<0><<<N / 2, BLK, 0, stream>>>(x1, A2, B2, w_msg2, w_pos2, b_pos2,
                                         (float*)d_out,
                                         nullptr, nullptr, nullptr, nullptr,
                                         nullptr, nullptr, nullptr);
}

// Round 9
// 39.735 us; speedup vs baseline: 1.1118x; 1.1118x over previous
//
#include <hip/hip_runtime.h>

#define N    1024
#define HD   64
#define MD   32
#define BLK  256        // k_p0 block
#define BLKP 512        // pair-kernel block: 8 waves -> 4 waves/SIMD resident
#define WROW (2 * HD + 1)   // 129, w_msg row stride

// ---------------------------------------------------------------------------
// P0: h0 = feat + posenc; A1/B1 projections. One block per 4 rows.
// ---------------------------------------------------------------------------
__global__ __launch_bounds__(BLK) void k_p0(const float* __restrict__ feat,
                                            const float* __restrict__ wmsg,
                                            const float* __restrict__ bmsg,
                                            float* __restrict__ h0,
                                            float* __restrict__ A,
                                            float* __restrict__ Bb)
{
    __shared__ float scr[4160 + 4 * HD];
    const int tid = threadIdx.x;
    const int n0  = blockIdx.x * 4;

    for (int u = tid; u < MD * WROW; u += BLK) scr[u] = wmsg[u];   // 4128 floats
    float* hrow = scr + 4160;
    {
        const int n = n0 + (tid >> 6), d = tid & 63;
        const float div = expf((float)(d & ~1) * (-9.210340371976184f / 64.0f));
        const float ang = (float)n * div;
        const float pe  = (d & 1) ? cosf(ang) : sinf(ang);
        const float hv  = feat[n * HD + d] + pe;
        h0[n * HD + d] = hv;
        hrow[tid] = hv;
    }
    __syncthreads();
    if (tid < 4 * MD) {
        const int nl = tid >> 5, m = tid & 31;
        const float* wa = scr + m * WROW;          // stride 129: conflict-free
        const float* hr = hrow + nl * HD;
        float sa = 0.f, sb = bmsg[m];
#pragma unroll
        for (int c = 0; c < HD; c++) {
            const float hv = hr[c];
            sa = fmaf(hv, wa[c], sa);
            sb = fmaf(hv, wa[HD + c], sb);
        }
        const int n = n0 + nl;
        A[n * MD + m]  = sa;
        Bb[n * MD + m] = sb;
    }
}

// ---------------------------------------------------------------------------
// Pair kernel: one block (512 thr = 8 waves) per row-pair (iA, iB = iA+N/2).
// Wave w owns j in [w*128, w*128+128).  Lane map: kq = lane>>3 (4 k's via one
// float4 A-load), jslot = lane&7 (8 j per wave-iter).
// m = relu(A[j][k] + Bi[k] + d2*wd[k]);  P[k][c] += m * r_c ; wp folded after.
// x_out[i] = x[i] + (S_k wp_ck P_kc + bp_c (Sx_c - N x_ic)) / (N-1)
// LAYER1 additionally produces msum (diag-corrected), h1, and A2/B2 for iA,iB.
// ---------------------------------------------------------------------------
template<int LAYER1>
__global__ __launch_bounds__(BLKP) void k_pair(
    const float* __restrict__ xsrc, const float* __restrict__ Aap,
    const float* __restrict__ Bbp, const float* __restrict__ wmsg,
    const float* __restrict__ wpos, const float* __restrict__ bpos,
    float* __restrict__ xout,
    const float* __restrict__ h0, const float* __restrict__ wf,
    const float* __restrict__ bf, const float* __restrict__ wmsg2,
    const float* __restrict__ bmsg2, float* __restrict__ A2,
    float* __restrict__ B2)
{
    const int tid   = threadIdx.x;
    const int wid   = tid >> 6;         // 0..7
    const int lane  = tid & 63;
    const int jslot = lane & 7;
    const int kq    = lane >> 3;        // k = kq*4 .. kq*4+3

    __shared__ float4 rd[2 * N];        // 32 KB: rdA | rdB (contiguous scratch)
    __shared__ float  wacc[8][8];
    __shared__ float  msAl[8][MD];
    __shared__ float  msBl[8][MD];
    __shared__ float  SxL[3];
    __shared__ float  msF[2][MD];
    __shared__ float  h0r[2][HD];
    __shared__ float  h1r[2][HD];
    float4* rdA = rd;
    float4* rdB = rd + N;

    const int iA = blockIdx.x, iB = blockIdx.x + N / 2;
    const float xiA0 = xsrc[iA * 3 + 0], xiA1 = xsrc[iA * 3 + 1], xiA2 = xsrc[iA * 3 + 2];
    const float xiB0 = xsrc[iB * 3 + 0], xiB1 = xsrc[iB * 3 + 1], xiB2 = xsrc[iB * 3 + 2];

    // ---- stage r/d2 tables for both rows; accumulate column-sum of x ----
    float sx0 = 0.f, sx1 = 0.f, sx2 = 0.f;
#pragma unroll
    for (int q = 0; q < N / BLKP; q++) {
        const int j = q * BLKP + tid;
        const float xj0 = xsrc[j * 3 + 0];
        const float xj1 = xsrc[j * 3 + 1];
        const float xj2 = xsrc[j * 3 + 2];
        sx0 += xj0; sx1 += xj1; sx2 += xj2;
        float r0 = xj0 - xiA0, r1 = xj1 - xiA1, r2 = xj2 - xiA2;
        rdA[j] = make_float4(r0, r1, r2, fmaf(r0, r0, fmaf(r1, r1, r2 * r2)));
        r0 = xj0 - xiB0; r1 = xj1 - xiB1; r2 = xj2 - xiB2;
        rdB[j] = make_float4(r0, r1, r2, fmaf(r0, r0, fmaf(r1, r1, r2 * r2)));
    }
#pragma unroll
    for (int off = 32; off > 0; off >>= 1) {
        sx0 += __shfl_xor(sx0, off);
        sx1 += __shfl_xor(sx1, off);
        sx2 += __shfl_xor(sx2, off);
    }
    if (lane == 0) { wacc[wid][0] = sx0; wacc[wid][1] = sx1; wacc[wid][2] = sx2; }
    __syncthreads();                       // rd tables + sx partials ready
    if (tid == 0) {
        float s0 = 0.f, s1 = 0.f, s2 = 0.f;
#pragma unroll
        for (int w = 0; w < 8; w++) { s0 += wacc[w][0]; s1 += wacc[w][1]; s2 += wacc[w][2]; }
        SxL[0] = s0; SxL[1] = s1; SxL[2] = s2;
    }

    // ---- per-lane weights for the 4 owned k's ----
    const float4 biA4 = *(const float4*)(Bbp + iA * MD + kq * 4);
    const float4 biB4 = *(const float4*)(Bbp + iB * MD + kq * 4);
    const float4 wpx4 = *(const float4*)(wpos + kq * 4);
    const float4 wpy4 = *(const float4*)(wpos + MD + kq * 4);
    const float4 wpz4 = *(const float4*)(wpos + 2 * MD + kq * 4);
    float wd4[4];
#pragma unroll
    for (int kk = 0; kk < 4; kk++) wd4[kk] = wmsg[(kq * 4 + kk) * WROW + 2 * HD];
    const float biA[4] = {biA4.x, biA4.y, biA4.z, biA4.w};
    const float biB[4] = {biB4.x, biB4.y, biB4.z, biB4.w};
    const float wpx[4] = {wpx4.x, wpx4.y, wpx4.z, wpx4.w};
    const float wpy[4] = {wpy4.x, wpy4.y, wpy4.z, wpy4.w};
    const float wpz[4] = {wpz4.x, wpz4.y, wpz4.z, wpz4.w};

    float PAx[4] = {0,0,0,0}, PAy[4] = {0,0,0,0}, PAz[4] = {0,0,0,0};
    float PBx[4] = {0,0,0,0}, PBy[4] = {0,0,0,0}, PBz[4] = {0,0,0,0};
    float msA[4] = {0,0,0,0}, msB[4] = {0,0,0,0};

    const int jb = wid * (N / 8);          // 128 j per wave
#pragma unroll 8
    for (int it = 0; it < N / 8 / 8; it++) {
        const int j = jb + it * 8 + jslot;
        const float4 a4 = *(const float4*)(Aap + j * MD + kq * 4);
        const float4 fA = rdA[j];          // 8-way broadcast per address
        const float4 fB = rdB[j];
        const float av[4] = {a4.x, a4.y, a4.z, a4.w};
#pragma unroll
        for (int kk = 0; kk < 4; kk++) {
            const float mA = fmaxf(fmaf(fA.w, wd4[kk], av[kk] + biA[kk]), 0.f);
            const float mB = fmaxf(fmaf(fB.w, wd4[kk], av[kk] + biB[kk]), 0.f);
            if (LAYER1) { msA[kk] += mA; msB[kk] += mB; }
            PAx[kk] = fmaf(mA, fA.x, PAx[kk]);
            PAy[kk] = fmaf(mA, fA.y, PAy[kk]);
            PAz[kk] = fmaf(mA, fA.z, PAz[kk]);
            PBx[kk] = fmaf(mB, fB.x, PBx[kk]);
            PBy[kk] = fmaf(mB, fB.y, PBy[kk]);
            PBz[kk] = fmaf(mB, fB.z, PBz[kk]);
        }
    }

    // ---- fold wp per lane, then reduce across 64 lanes ----
    float vA0 = 0.f, vA1 = 0.f, vA2 = 0.f, vB0 = 0.f, vB1 = 0.f, vB2 = 0.f;
#pragma unroll
    for (int kk = 0; kk < 4; kk++) {
        vA0 = fmaf(PAx[kk], wpx[kk], vA0);
        vA1 = fmaf(PAy[kk], wpy[kk], vA1);
        vA2 = fmaf(PAz[kk], wpz[kk], vA2);
        vB0 = fmaf(PBx[kk], wpx[kk], vB0);
        vB1 = fmaf(PBy[kk], wpy[kk], vB1);
        vB2 = fmaf(PBz[kk], wpz[kk], vB2);
    }
#pragma unroll
    for (int off = 32; off > 0; off >>= 1) {
        vA0 += __shfl_xor(vA0, off); vA1 += __shfl_xor(vA1, off); vA2 += __shfl_xor(vA2, off);
        vB0 += __shfl_xor(vB0, off); vB1 += __shfl_xor(vB1, off); vB2 += __shfl_xor(vB2, off);
    }
    if (LAYER1) {
        // reduce msum over the 8 jslots (lane bits 0..2)
#pragma unroll
        for (int off = 1; off <= 4; off <<= 1) {
#pragma unroll
            for (int kk = 0; kk < 4; kk++) {
                msA[kk] += __shfl_xor(msA[kk], off);
                msB[kk] += __shfl_xor(msB[kk], off);
            }
        }
    }
    __syncthreads();                       // wacc consumed into SxL; reusable
    if (lane == 0) {
        wacc[wid][0] = vA0; wacc[wid][1] = vA1; wacc[wid][2] = vA2;
        wacc[wid][3] = vB0; wacc[wid][4] = vB1; wacc[wid][5] = vB2;
    }
    if (LAYER1 && jslot == 0) {
#pragma unroll
        for (int kk = 0; kk < 4; kk++) {
            msAl[wid][kq * 4 + kk] = msA[kk];
            msBl[wid][kq * 4 + kk] = msB[kk];
        }
    }
    __syncthreads();                       // epilogue data ready

    if (tid == 0) {
        const float bp0 = bpos[0], bp1 = bpos[1], bp2 = bpos[2];
        float aA0 = 0.f, aA1 = 0.f, aA2 = 0.f, aB0 = 0.f, aB1 = 0.f, aB2 = 0.f;
#pragma unroll
        for (int w = 0; w < 8; w++) {
            aA0 += wacc[w][0]; aA1 += wacc[w][1]; aA2 += wacc[w][2];
            aB0 += wacc[w][3]; aB1 += wacc[w][4]; aB2 += wacc[w][5];
        }
        const float inv = 1.0f / 1023.0f;
        xout[iA * 3 + 0] = xiA0 + (aA0 + bp0 * (SxL[0] - (float)N * xiA0)) * inv;
        xout[iA * 3 + 1] = xiA1 + (aA1 + bp1 * (SxL[1] - (float)N * xiA1)) * inv;
        xout[iA * 3 + 2] = xiA2 + (aA2 + bp2 * (SxL[2] - (float)N * xiA2)) * inv;
        xout[iB * 3 + 0] = xiB0 + (aB0 + bp0 * (SxL[0] - (float)N * xiB0)) * inv;
        xout[iB * 3 + 1] = xiB1 + (aB1 + bp1 * (SxL[1] - (float)N * xiB1)) * inv;
        xout[iB * 3 + 2] = xiB2 + (aB2 + bp2 * (SxL[2] - (float)N * xiB2)) * inv;
    }

    if (LAYER1) {
        // ---- fused h-update + layer-2 A/B projections for rows iA, iB ----
        float* scr = (float*)rd;           // 8192 floats free after main loop
        if (tid < 2 * MD) {                // msum rows with diagonal correction
            const int row = tid >> 5, k = tid & 31;
            const int i = row ? iB : iA;
            const float (*ml)[MD] = row ? msBl : msAl;
            float s = 0.f;
#pragma unroll
            for (int w = 0; w < 8; w++) s += ml[w][k];
            s -= fmaxf(Aap[i * MD + k] + Bbp[i * MD + k], 0.f);   // d2=0 at j==i
            msF[row][k] = s;
        }
        for (int u = tid; u < HD * (HD + MD); u += BLKP) {         // stage wf
            const int o = u / (HD + MD), c = u - o * (HD + MD);
            scr[o * 97 + c] = wf[u];
        }
        if (tid < 2 * HD) {
            const int row = tid >> 6, d = tid & 63;
            h0r[row][d] = h0[(row ? iB : iA) * HD + d];
        }
        __syncthreads();
        if (tid < 2 * HD) {                // h1 rows
            const int row = tid >> 6, o = tid & 63;
            const float* w = scr + o * 97;
            float s = bf[o];
#pragma unroll
            for (int c = 0; c < HD; c++) s = fmaf(h0r[row][c], w[c], s);
#pragma unroll
            for (int k = 0; k < MD; k++) s = fmaf(msF[row][k], w[HD + k], s);
            h1r[row][o] = fmaxf(s, 0.f);
        }
        __syncthreads();
        for (int u = tid; u < MD * WROW; u += BLKP) scr[u] = wmsg2[u];
        __syncthreads();
        if (tid < 2 * MD) {                // A2/B2 rows
            const int row = tid >> 5, m = tid & 31;
            const float* wa = scr + m * WROW;
            const float* hr = h1r[row];
            float sa = 0.f, sb = bmsg2[m];
#pragma unroll
            for (int c = 0; c < HD; c++) {
                const float hv = hr[c];
                sa = fmaf(hv, wa[c], sa);
                sb = fmaf(hv, wa[HD + c], sb);
            }
            const int i = row ? iB : iA;
            A2[i * MD + m] = sa;
            B2[i * MD + m] = sb;
        }
    }
}

// ---------------------------------------------------------------------------
extern "C" void kernel_launch(void* const* d_in, const int* in_sizes, int n_in,
                              void* d_out, int out_size, void* d_ws, size_t ws_size,
                              hipStream_t stream)
{
    const float* pos     = (const float*)d_in[0];
    const float* feat    = (const float*)d_in[1];
    const float* w_msg1  = (const float*)d_in[3];
    const float* b_msg1  = (const float*)d_in[4];
    const float* w_pos1  = (const float*)d_in[5];
    const float* b_pos1  = (const float*)d_in[6];
    const float* w_feat1 = (const float*)d_in[7];
    const float* b_feat1 = (const float*)d_in[8];
    const float* w_msg2  = (const float*)d_in[9];
    const float* b_msg2  = (const float*)d_in[10];
    const float* w_pos2  = (const float*)d_in[11];
    const float* b_pos2  = (const float*)d_in[12];

    float* ws  = (float*)d_ws;
    float* h0  = ws;                 // N*HD
    float* A1  = h0  + N * HD;       // N*MD
    float* B1  = A1  + N * MD;
    float* x1  = B1  + N * MD;       // N*4 (padded)
    float* A2  = x1  + N * 4;
    float* B2  = A2  + N * MD;

    k_p0<<<N / 4, BLK, 0, stream>>>(feat, w_msg1, b_msg1, h0, A1, B1);
    k_pair<1><<<N / 2, BLKP, 0, stream>>>(pos, A1, B1, w_msg1, w_pos1, b_pos1, x1,
                                          h0, w_feat1, b_feat1, w_msg2, b_msg2, A2, B2);
    k_pair<0><<<N / 2, BLKP, 0, stream>>>(x1, A2, B2, w_msg2, w_pos2, b_pos2,
                                          (float*)d_out,
                                          nullptr, nullptr, nullptr, nullptr,
                                          nullptr, nullptr, nullptr);
}